// Round 23
// baseline (284.182 us; speedup 1.0000x reference)
//
#include <hip/hip_runtime.h>
#include <cmath>

// B=2, S=4096, DM=768, H=12, FF=3072, BLOCK=64, NB=64, R=3, d=64
// Round 23: W1 -> 8-phase counted-vmcnt 256x256 GEMM (T3+T4 proper): 512 thr,
// 2 dbuf x 64KB, per-phase {stage 1 half-tile || ds_read || 16 MFMA || barrier},
// vmcnt(4)/(2) at phase ends 1/3/5/7 (never 0 mid-loop). QKV/W2/attn unchanged
// from round 22 (280.3 us baseline).

typedef unsigned short bf;
typedef __attribute__((ext_vector_type(8))) short bf16x8;
typedef __attribute__((ext_vector_type(4))) float f32x4;

__device__ __forceinline__ float bf2f(bf u) { return __uint_as_float(((unsigned)u) << 16); }
__device__ __forceinline__ bf f2bf(float f) {
  unsigned x = __float_as_uint(f);
  x += 0x7FFFu + ((x >> 16) & 1u);   // round-to-nearest-even
  return (bf)(x >> 16);
}

// async global->LDS, 16B per lane; LDS dest = wave-uniform base + lane*16
__device__ __forceinline__ void gload16(const bf* g, char* lds) {
  __builtin_amdgcn_global_load_lds(
      (const __attribute__((address_space(1))) void*)g,
      (__attribute__((address_space(3))) void*)lds, 16, 0, 0);
}

// ---- x f32 -> bf16 (8/thread) ----
__global__ __launch_bounds__(256) void cvt_x_k(const float* __restrict__ X,
                                               bf* __restrict__ xb)
{
  size_t i = ((size_t)blockIdx.x * 256 + threadIdx.x) * 8;
  float4 f0 = *(const float4*)&X[i];
  float4 f1 = *(const float4*)&X[i + 4];
  *(ushort4*)&xb[i]     = make_ushort4(f2bf(f0.x), f2bf(f0.y), f2bf(f0.z), f2bf(f0.w));
  *(ushort4*)&xb[i + 4] = make_ushort4(f2bf(f1.x), f2bf(f1.y), f2bf(f1.z), f2bf(f1.w));
}

// ---- W [K][N] f32 -> Wt [N][K] bf16, 64x64 LDS tile ----
__global__ __launch_bounds__(256) void tconv_k(const float* __restrict__ W,
                                               bf* __restrict__ Wt, int K, int N)
{
  __shared__ float tile[64][65];
  const int t = threadIdx.x;
  const int bn = blockIdx.x * 64, bk = blockIdx.y * 64;
  const int r = t >> 2, c0 = (t & 3) * 16;
  #pragma unroll
  for (int i = 0; i < 4; ++i) {
    float4 f = *(const float4*)&W[(size_t)(bk + r) * N + bn + c0 + i * 4];
    tile[r][c0 + i*4 + 0] = f.x; tile[r][c0 + i*4 + 1] = f.y;
    tile[r][c0 + i*4 + 2] = f.z; tile[r][c0 + i*4 + 3] = f.w;
  }
  __syncthreads();
  #pragma unroll
  for (int i = 0; i < 4; ++i) {
    int c = c0 + i * 4;
    ushort4 u = make_ushort4(f2bf(tile[c + 0][r]), f2bf(tile[c + 1][r]),
                             f2bf(tile[c + 2][r]), f2bf(tile[c + 3][r]));
    *(ushort4*)&Wt[(size_t)(bn + r) * K + bk + c] = u;
  }
}

// ---- 3x [768][768] transpose-convert in one launch ----
__global__ __launch_bounds__(256) void tconv3_k(const float* __restrict__ Wq,
                                                const float* __restrict__ Wk,
                                                const float* __restrict__ Wv,
                                                bf* __restrict__ Wt)
{
  __shared__ float tile[64][65];
  const float* W = (blockIdx.z == 0) ? Wq : ((blockIdx.z == 1) ? Wk : Wv);
  bf* dst = Wt + (size_t)blockIdx.z * 589824;
  const int t = threadIdx.x;
  const int bn = blockIdx.x * 64, bk = blockIdx.y * 64;
  const int r = t >> 2, c0 = (t & 3) * 16;
  #pragma unroll
  for (int i = 0; i < 4; ++i) {
    float4 f = *(const float4*)&W[(size_t)(bk + r) * 768 + bn + c0 + i * 4];
    tile[r][c0 + i*4 + 0] = f.x; tile[r][c0 + i*4 + 1] = f.y;
    tile[r][c0 + i*4 + 2] = f.z; tile[r][c0 + i*4 + 3] = f.w;
  }
  __syncthreads();
  #pragma unroll
  for (int i = 0; i < 4; ++i) {
    int c = c0 + i * 4;
    ushort4 u = make_ushort4(f2bf(tile[c + 0][r]), f2bf(tile[c + 1][r]),
                             f2bf(tile[c + 2][r]), f2bf(tile[c + 3][r]));
    *(ushort4*)&dst[(size_t)(bn + r) * 768 + bk + c] = u;
  }
}

// ---- 8-phase counted-vmcnt 256x256 GEMM (W1: bias+GELU, bf16 out) ----
// A[M][K] bf16, Bt[N][ldbt] bf16. 512 threads: 8 waves 2Mx4N, 128x64/wave.
// Wave n-frags strided: col = q*64 + wn*16 (phase q touches only B-half q>>1).
__global__ __launch_bounds__(512) void gemm8_k(
    const bf* __restrict__ A, const bf* __restrict__ Bt,
    const float* __restrict__ bias, bf* __restrict__ C,
    int M, int N, int K, int ldbt)
{
  __shared__ char smem[131072];  // dbuf d at d*65536: A 32KB, B 32KB
  const int t = threadIdx.x;
  const int bm = blockIdx.y * 256, bn = blockIdx.x * 256;
  const int lane = t & 63, wid = t >> 6;
  const int wm = wid >> 2, wn = wid & 3;
  const int fr = lane & 15, fq = lane >> 4;

  f32x4 acc[8][4];
  #pragma unroll
  for (int i = 0; i < 8; ++i)
    #pragma unroll
    for (int q = 0; q < 4; ++q) acc[i][q] = (f32x4){0.f, 0.f, 0.f, 0.f};

  // stage one 128x64 half-tile (2 gloads/thread). which: 0=A0,1=A1,2=B0,3=B1
  auto STAGE_HALF = [&](int d, int which, int kt) {
    char* base = smem + d * 65536 + ((which >= 2) ? 32768 : 0);
    int h = which & 1;
    const bf* P = (which >= 2) ? Bt : A;
    int ld  = (which >= 2) ? ldbt : K;
    int rc0 = ((which >= 2) ? bn : bm) + h * 128;
    int k0  = kt * 64;
    #pragma unroll
    for (int c = 0; c < 2; ++c) {
      int idx = c * 512 + t;
      int rl = idx >> 3, ks = idx & 7;
      gload16(P + (size_t)(rc0 + rl) * ld + k0 + ((ks ^ (rl & 7)) << 3),
              base + h * 16384 + (c * 512 + wid * 64) * 16);
    }
  };

  const int T = K >> 6;   // even (768/64 = 12)
  // prologue: stage kt0 (A0,A1,B0,B1) into dbuf0
  STAGE_HALF(0, 0, 0); STAGE_HALF(0, 1, 0); STAGE_HALF(0, 2, 0); STAGE_HALF(0, 3, 0);
  asm volatile("s_waitcnt vmcnt(2)" ::: "memory");   // A0,A1,B0 landed (B1 in flight)
  __builtin_amdgcn_s_barrier();
  __builtin_amdgcn_sched_barrier(0);

  bf16x8 ac[2][8];   // A-frag cache for the current K-tile (loaded at q==0)

  for (int i2 = 0; i2 < T; i2 += 2) {
    #pragma unroll
    for (int p = 0; p < 8; ++p) {
      constexpr int P8 = 1;  (void)P8;
      const int d = p >> 2;            // dbuf being computed
      const int q = p & 3;             // n-quadrant
      // stage exactly one half-tile
      if (p < 4) { if (i2 + 1 < T) STAGE_HALF(1, p, i2 + 1); }
      else       { if (i2 + 2 < T) STAGE_HALF(0, p - 4, i2 + 2); }
      __builtin_amdgcn_sched_barrier(0);
      char* sA = smem + d * 65536;
      char* sB = sA + 32768;
      if (q == 0) {
        #pragma unroll
        for (int kh = 0; kh < 2; ++kh)
          #pragma unroll
          for (int i = 0; i < 8; ++i) {
            int row = wm * 128 + i * 16 + fr;
            ac[kh][i] = *(const bf16x8*)(sA + row * 128 +
                          ((kh * 64 + fq * 16) ^ ((row & 7) << 4)));
          }
      }
      bf16x8 bfr[2];
      #pragma unroll
      for (int kh = 0; kh < 2; ++kh) {
        int col = q * 64 + wn * 16 + fr;
        bfr[kh] = *(const bf16x8*)(sB + col * 128 +
                      ((kh * 64 + fq * 16) ^ ((col & 7) << 4)));
      }
      __builtin_amdgcn_s_setprio(1);
      #pragma unroll
      for (int kh = 0; kh < 2; ++kh)
        #pragma unroll
        for (int i = 0; i < 8; ++i)
          acc[i][q] = __builtin_amdgcn_mfma_f32_16x16x32_bf16(ac[kh][i], bfr[kh], acc[i][q], 0, 0, 0);
      __builtin_amdgcn_s_setprio(0);
      __builtin_amdgcn_sched_barrier(0);
      // counted waits (never 0 mid-loop; 0 only when no stage covers the gap)
      if (p == 1) {
        asm volatile("s_waitcnt vmcnt(4)" ::: "memory");          // B1 of dbuf0 landed
      } else if (p == 3) {
        asm volatile("s_waitcnt vmcnt(2)" ::: "memory");          // dbuf1 A0,A1,B0 landed
      } else if (p == 5) {
        if (i2 + 2 < T) { asm volatile("s_waitcnt vmcnt(4)" ::: "memory"); }
        else            { asm volatile("s_waitcnt vmcnt(0)" ::: "memory"); }
      } else if (p == 7) {
        if (i2 + 2 < T) { asm volatile("s_waitcnt vmcnt(2)" ::: "memory"); }
        else            { asm volatile("s_waitcnt vmcnt(0)" ::: "memory"); }
      }
      __builtin_amdgcn_s_barrier();
      __builtin_amdgcn_sched_barrier(0);
    }
  }
  // epilogue: bias + GELU + bf16 store
  #pragma unroll
  for (int q = 0; q < 4; ++q) {
    int col = bn + q * 64 + wn * 16 + fr;
    float bias_v = bias[col];
    #pragma unroll
    for (int i = 0; i < 8; ++i) {
      int row0 = bm + wm * 128 + i * 16 + fq * 4;
      #pragma unroll
      for (int r = 0; r < 4; ++r) {
        float v = acc[i][q][r] + bias_v;
        v = 0.5f * v * (1.0f + erff(v * 0.70710678118654752f));
        C[(size_t)(row0 + r) * N + col] = f2bf(v);
      }
    }
  }
}

// ---- 2-phase pipelined GEMM with T2 swizzle (round-17 proven; W2) ----
template <int BN, typename TC>
__global__ __launch_bounds__(256) void gl_gemm_k(
    const bf* __restrict__ A, const bf* __restrict__ Bt,
    const float* __restrict__ bias, TC* __restrict__ C,
    int M, int N, int K, int ldbt, int ep)
{
  constexpr int NJ = BN / 32;
  constexpr int ASZ = 16384;
  constexpr int BSZ = BN * 128;
  __shared__ char smem[2 * (ASZ + BSZ)];
  const int t = threadIdx.x;
  const int bm = blockIdx.y * 128, bn = blockIdx.x * BN;
  const int lane = t & 63, wid = t >> 6;
  const int wm = wid >> 1, wn = wid & 1;
  const int fr = lane & 15, fq = lane >> 4;
  const int lr = lane >> 3;
  const int lksw = (((lane & 7) ^ lr) << 3);

  f32x4 acc[4][NJ];
  #pragma unroll
  for (int i = 0; i < 4; ++i)
    #pragma unroll
    for (int j = 0; j < NJ; ++j) acc[i][j] = (f32x4){0.f, 0.f, 0.f, 0.f};

  auto STAGE = [&](int p, int k0) {
    char* sA = smem + p * (ASZ + BSZ);
    char* sB = sA + ASZ;
    #pragma unroll
    for (int c = 0; c < 4; ++c) {
      int chunk = wid * 4 + c;
      gload16(A + (size_t)(bm + chunk * 8 + lr) * K + k0 + lksw, sA + chunk * 1024);
    }
    #pragma unroll
    for (int c = 0; c < NJ; ++c) {
      int chunk = wid * NJ + c;
      gload16(Bt + (size_t)(bn + chunk * 8 + lr) * ldbt + k0 + lksw, sB + chunk * 1024);
    }
  };

  const int T = K >> 6;
  STAGE(0, 0);
  asm volatile("s_waitcnt vmcnt(0)" ::: "memory");
  __builtin_amdgcn_s_barrier();
  __builtin_amdgcn_sched_barrier(0);
  int cur = 0;
  for (int tt = 0; tt < T; ++tt) {
    if (tt + 1 < T) STAGE(cur ^ 1, (tt + 1) * 64);
    __builtin_amdgcn_sched_barrier(0);
    char* sA = smem + cur * (ASZ + BSZ);
    char* sB = sA + ASZ;
    __builtin_amdgcn_s_setprio(1);
    #pragma unroll
    for (int kk = 0; kk < 2; ++kk) {
      const int kb = kk * 64 + fq * 16;
      bf16x8 a[4], b[NJ];
      #pragma unroll
      for (int i = 0; i < 4; ++i) {
        int row = wm * 64 + i * 16 + fr;
        a[i] = *(const bf16x8*)(sA + row * 128 + (kb ^ ((row & 7) << 4)));
      }
      #pragma unroll
      for (int j = 0; j < NJ; ++j) {
        int col = wn * (BN / 2) + j * 16 + fr;
        b[j] = *(const bf16x8*)(sB + col * 128 + (kb ^ ((col & 7) << 4)));
      }
      #pragma unroll
      for (int i = 0; i < 4; ++i)
        #pragma unroll
        for (int j = 0; j < NJ; ++j)
          acc[i][j] = __builtin_amdgcn_mfma_f32_16x16x32_bf16(a[i], b[j], acc[i][j], 0, 0, 0);
    }
    __builtin_amdgcn_s_setprio(0);
    __builtin_amdgcn_sched_barrier(0);
    asm volatile("s_waitcnt vmcnt(0)" ::: "memory");
    __builtin_amdgcn_s_barrier();
    __builtin_amdgcn_sched_barrier(0);
    cur ^= 1;
  }
  #pragma unroll
  for (int j = 0; j < NJ; ++j) {
    int col = bn + wn * (BN / 2) + j * 16 + fr;
    float bias_v = bias ? bias[col] : 0.f;
    #pragma unroll
    for (int i = 0; i < 4; ++i) {
      int row0 = bm + wm * 64 + i * 16 + fq * 4;
      #pragma unroll
      for (int r = 0; r < 4; ++r) {
        float v = acc[i][j][r] + bias_v;
        if (ep == 1) v = 0.5f * v * (1.0f + erff(v * 0.70710678118654752f));
        if constexpr (sizeof(TC) == 2) C[(size_t)(row0 + r) * N + col] = f2bf(v);
        else                           C[(size_t)(row0 + r) * N + col] = v;
      }
    }
  }
}

// ---- QKV GEMM, 2-phase + swizzle (round-17 proven) ----
__global__ __launch_bounds__(256) void qkv_gl_k(
    const bf* __restrict__ A, const bf* __restrict__ Bt,
    const float* __restrict__ bq, const float* __restrict__ bk,
    const float* __restrict__ bv,
    bf* __restrict__ Qo, bf* __restrict__ Ko, bf* __restrict__ Vo)
{
  constexpr int ASZ = 16384, BSZ = 16384;
  __shared__ char smem[2 * (ASZ + BSZ)];
  const int t = threadIdx.x;
  const int bm = blockIdx.y * 128, bn = blockIdx.x * 128;
  const int lane = t & 63, wid = t >> 6;
  const int wm = wid >> 1, wn = wid & 1;
  const int fr = lane & 15, fq = lane >> 4;
  const int lr = lane >> 3;
  const int lksw = (((lane & 7) ^ lr) << 3);
  const int K = 768;

  f32x4 acc[4][4];
  #pragma unroll
  for (int i = 0; i < 4; ++i)
    #pragma unroll
    for (int j = 0; j < 4; ++j) acc[i][j] = (f32x4){0.f, 0.f, 0.f, 0.f};

  auto STAGE = [&](int p, int k0) {
    char* sA = smem + p * (ASZ + BSZ);
    char* sB = sA + ASZ;
    #pragma unroll
    for (int c = 0; c < 4; ++c) {
      int chunk = wid * 4 + c;
      gload16(A + (size_t)(bm + chunk * 8 + lr) * K + k0 + lksw, sA + chunk * 1024);
    }
    #pragma unroll
    for (int c = 0; c < 4; ++c) {
      int chunk = wid * 4 + c;
      gload16(Bt + (size_t)(bn + chunk * 8 + lr) * K + k0 + lksw, sB + chunk * 1024);
    }
  };

  STAGE(0, 0);
  asm volatile("s_waitcnt vmcnt(0)" ::: "memory");
  __builtin_amdgcn_s_barrier();
  __builtin_amdgcn_sched_barrier(0);
  int cur = 0;
  for (int tt = 0; tt < 12; ++tt) {
    if (tt + 1 < 12) STAGE(cur ^ 1, (tt + 1) * 64);
    __builtin_amdgcn_sched_barrier(0);
    char* sA = smem + cur * (ASZ + BSZ);
    char* sB = sA + ASZ;
    __builtin_amdgcn_s_setprio(1);
    #pragma unroll
    for (int kk = 0; kk < 2; ++kk) {
      const int kb = kk * 64 + fq * 16;
      bf16x8 a[4], b[4];
      #pragma unroll
      for (int i = 0; i < 4; ++i) {
        int row = wm * 64 + i * 16 + fr;
        a[i] = *(const bf16x8*)(sA + row * 128 + (kb ^ ((row & 7) << 4)));
      }
      #pragma unroll
      for (int j = 0; j < 4; ++j) {
        int col = wn * 64 + j * 16 + fr;
        b[j] = *(const bf16x8*)(sB + col * 128 + (kb ^ ((col & 7) << 4)));
      }
      #pragma unroll
      for (int i = 0; i < 4; ++i)
        #pragma unroll
        for (int j = 0; j < 4; ++j)
          acc[i][j] = __builtin_amdgcn_mfma_f32_16x16x32_bf16(a[i], b[j], acc[i][j], 0, 0, 0);
    }
    __builtin_amdgcn_s_setprio(0);
    __builtin_amdgcn_sched_barrier(0);
    asm volatile("s_waitcnt vmcnt(0)" ::: "memory");
    __builtin_amdgcn_s_barrier();
    __builtin_amdgcn_sched_barrier(0);
    cur ^= 1;
  }
  const int seg = bn / 768;
  const int cb  = bn - seg * 768;
  bf* dst = (seg == 0) ? Qo : ((seg == 1) ? Ko : Vo);
  const float* bias = (seg == 0) ? bq : ((seg == 1) ? bk : bv);
  #pragma unroll
  for (int j = 0; j < 4; ++j) {
    int col = cb + wn * 64 + j * 16 + fr;
    float bias_v = bias[col];
    #pragma unroll
    for (int i = 0; i < 4; ++i) {
      int row0 = bm + wm * 64 + i * 16 + fq * 4;
      #pragma unroll
      for (int r = 0; r < 4; ++r)
        dst[(size_t)(row0 + r) * 768 + col] = f2bf(acc[i][j][r] + bias_v);
    }
  }
}

// stage one prefetched K/V block into LDS buffers
__device__ __forceinline__ void stage_kv(char* bK, char* bVT,
    int kkey, int kd0, int vkey, int w,
    uint4 k0, uint4 k1, uint4 v0, uint4 v1)
{
  const int sw = (kkey & 7) << 4;
  *(uint4*)(bK + kkey * 128 + ((2 * kd0) ^ sw))      = k0;
  *(uint4*)(bK + kkey * 128 + ((2 * kd0 + 16) ^ sw)) = k1;
  union { uint4 q; unsigned short s[8]; } a, c;
  a.q = v0; c.q = v1;
  #pragma unroll
  for (int i = 0; i < 8; ++i) {
    int d = w * 16 + i;
    *(unsigned short*)(bVT + d * 128 + ((2 * vkey) ^ ((d & 7) << 4))) = a.s[i];
  }
  #pragma unroll
  for (int i = 0; i < 8; ++i) {
    int d = w * 16 + 8 + i;
    *(unsigned short*)(bVT + d * 128 + ((2 * vkey) ^ ((d & 7) << 4))) = c.s[i];
  }
}

// ---------------- BigBird attention v5 (unchanged) ----------------
__global__ __launch_bounds__(256) void attn5_kernel(
    const bf* __restrict__ Q, const bf* __restrict__ K,
    const bf* __restrict__ V, const int* __restrict__ rnd,
    float* __restrict__ ctx, float* __restrict__ part, int nseg)
{
  __shared__ char sQP[8192];
  __shared__ char sKV[2][16384];
  __shared__ int klist[8];
  const int t = threadIdx.x;
  const int lane = t & 63, w = t >> 6;
  const int fr = lane & 15, fq = lane >> 4;
  const int wg = blockIdx.x;
  const int nheavy = 48 * nseg;
  const bool heavy = wg < nheavy;
  int b, h, n, nkb, seg = 0, hidx = 0, segBase = 0;
  if (heavy) {
    hidx = wg / nseg; seg = wg - hidx * nseg;
    n = (hidx & 1) ? 63 : 0;
    int bh = hidx >> 1; h = bh % 12; b = bh / 12;
    nkb = 64 / nseg; segBase = seg * nkb;
  } else {
    int idx = wg - nheavy;
    n = 1 + (idx % 62);
    int bh = idx / 62; h = bh % 12; b = bh / 12;
    nkb = (n == 1 || n == 62) ? 7 : 8;
    if (t == 0) {
      int cnt = 0;
      if (n == 1)       { klist[0]=0; klist[1]=1;  klist[2]=2;  klist[3]=63; cnt=4; }
      else if (n == 62) { klist[0]=0; klist[1]=61; klist[2]=62; klist[3]=63; cnt=4; }
      else              { klist[0]=0; klist[1]=n-1; klist[2]=n; klist[3]=n+1; cnt=4; }
      for (int j = 0; j < 3; ++j) klist[cnt++] = rnd[(h * 62 + (n - 1)) * 3 + j];
      if (n != 1 && n != 62) klist[cnt++] = 63;
    }
  }
  const size_t qbase = ((size_t)b * 4096 + (size_t)n * 64) * 768 + h * 64;

  {
    int row = t >> 2, d0 = (t & 3) * 16;
    const bf* qp = &Q[qbase + (size_t)row * 768 + d0];
    #pragma unroll
    for (int i = 0; i < 2; ++i) {
      int off = row * 128 + ((2 * (d0 + 8 * i)) ^ ((row & 7) << 4));
      *(uint4*)(sQP + off) = *(const uint4*)(qp + 8 * i);
    }
  }
  __syncthreads();
  bf16x8 qf[2];
  {
    int row = w * 16 + fr;
    qf[0] = *(const bf16x8*)(sQP + row * 128 + ((2 * (fq * 8))      ^ ((row & 7) << 4)));
    qf[1] = *(const bf16x8*)(sQP + row * 128 + ((2 * (32 + fq * 8)) ^ ((row & 7) << 4)));
  }

  const int kkey = t >> 2, kd0 = (t & 3) * 16;
  const int vkey = lane;

  uint4 pk0, pk1, pv0, pv1;
  {
    int kb = heavy ? segBase : klist[0];
    size_t kbase = ((size_t)b * 4096 + (size_t)kb * 64) * 768 + h * 64;
    const bf* kp = &K[kbase + (size_t)kkey * 768 + kd0];
    pk0 = *(const uint4*)kp;  pk1 = *(const uint4*)(kp + 8);
    const bf* vp = &V[kbase + (size_t)vkey * 768 + w * 16];
    pv0 = *(const uint4*)vp;  pv1 = *(const uint4*)(vp + 8);
  }
  stage_kv(sKV[0], sKV[0] + 8192, kkey, kd0, vkey, w, pk0, pk1, pv0, pv1);

  float m_r[4] = {-1e30f, -1e30f, -1e30f, -1e30f};
  float l_r[4] = {0.f, 0.f, 0.f, 0.f};
  f32x4 acc_o[4];
  #pragma unroll
  for (int j = 0; j < 4; ++j) acc_o[j] = (f32x4){0.f, 0.f, 0.f, 0.f};

  for (int ib = 0; ib < nkb; ++ib) {
    char* bK  = sKV[ib & 1];
    char* bVT = bK + 8192;
    const bool pfv = (ib + 1 < nkb);
    if (pfv) {
      int kb = heavy ? (segBase + ib + 1) : klist[ib + 1];
      size_t kbase = ((size_t)b * 4096 + (size_t)kb * 64) * 768 + h * 64;
      const bf* kp = &K[kbase + (size_t)kkey * 768 + kd0];
      pk0 = *(const uint4*)kp;  pk1 = *(const uint4*)(kp + 8);
      const bf* vp = &V[kbase + (size_t)vkey * 768 + w * 16];
      pv0 = *(const uint4*)vp;  pv1 = *(const uint4*)(vp + 8);
    }
    __syncthreads();
    f32x4 s4[4];
    #pragma unroll
    for (int j = 0; j < 4; ++j) s4[j] = (f32x4){0.f, 0.f, 0.f, 0.f};
    __builtin_amdgcn_s_setprio(1);
    #pragma unroll
    for (int kk = 0; kk < 2; ++kk) {
      #pragma unroll
      for (int j = 0; j < 4; ++j) {
        int key = j * 16 + fr;
        bf16x8 kf = *(const bf16x8*)(bK + key * 128 + ((2 * (kk * 32 + fq * 8)) ^ ((key & 7) << 4)));
        s4[j] = __builtin_amdgcn_mfma_f32_16x16x32_bf16(qf[kk], kf, s4[j], 0, 0, 0);
      }
    }
    __builtin_amdgcn_s_setprio(0);
    #pragma unroll
    for (int j = 0; j < 4; ++j) s4[j] *= 0.125f;
    float c_r[4];
    #pragma unroll
    for (int r = 0; r < 4; ++r) {
      float mx = fmaxf(fmaxf(s4[0][r], s4[1][r]), fmaxf(s4[2][r], s4[3][r]));
      #pragma unroll
      for (int m = 1; m < 16; m <<= 1) mx = fmaxf(mx, __shfl_xor(mx, m, 64));
      float mn = fmaxf(mx, m_r[r]);
      float c  = __expf(m_r[r] - mn);
      float p0 = __expf(s4[0][r] - mn), p1 = __expf(s4[1][r] - mn);
      float p2 = __expf(s4[2][r] - mn), p3 = __expf(s4[3][r] - mn);
      s4[0][r] = p0; s4[1][r] = p1; s4[2][r] = p2; s4[3][r] = p3;
      float sum = p0 + p1 + p2 + p3;
      #pragma unroll
      for (int m = 1; m < 16; m <<= 1) sum += __shfl_xor(sum, m, 64);
      l_r[r] = l_r[r] * c + sum;
      m_r[r] = mn;
      c_r[r] = c;
    }
    #pragma unroll
    for (int j = 0; j < 4; ++j)
      #pragma unroll
      for (int r = 0; r < 4; ++r) acc_o[j][r] *= c_r[r];
    #pragma unroll
    for (int r = 0; r < 4; ++r) {
      int prow = w * 16 + fq * 4 + r;
      int rs = prow * 128, sw = (prow & 7) << 4;
      #pragma unroll
      for (int j = 0; j < 4; ++j)
        *(unsigned short*)(sQP + rs + ((2 * (j * 16 + fr)) ^ sw)) = f2bf(s4[j][r]);
    }
    if (pfv)
      stage_kv(sKV[(ib & 1) ^ 1], sKV[(ib & 1) ^ 1] + 8192, kkey, kd0, vkey, w,
               pk0, pk1, pv0, pv1);
    __builtin_amdgcn_s_setprio(1);
    #pragma unroll
    for (int kk = 0; kk < 2; ++kk) {
      int prow = w * 16 + fr;
      bf16x8 pf8 = *(const bf16x8*)(sQP + prow * 128 + ((2 * (kk * 32 + fq * 8)) ^ ((prow & 7) << 4)));
      #pragma unroll
      for (int j = 0; j < 4; ++j) {
        int col = j * 16 + fr;
        bf16x8 vf = *(const bf16x8*)(bVT + col * 128 + ((2 * (kk * 32 + fq * 8)) ^ ((col & 7) << 4)));
        acc_o[j] = __builtin_amdgcn_mfma_f32_16x16x32_bf16(pf8, vf, acc_o[j], 0, 0, 0);
      }
    }
    __builtin_amdgcn_s_setprio(0);
  }
  if (heavy && nseg > 1) {
    float* pb = part + ((size_t)hidx * nseg + seg) * 4224;
    int row0 = w * 16 + fq * 4;
    #pragma unroll
    for (int r = 0; r < 4; ++r) {
      int row = row0 + r;
      if (fr == 0) { pb[4096 + row] = m_r[r]; pb[4160 + row] = l_r[r]; }
      #pragma unroll
      for (int j = 0; j < 4; ++j)
        pb[row * 64 + j * 16 + fr] = acc_o[j][r];
    }
  } else {
    int row0 = w * 16 + fq * 4;
    #pragma unroll
    for (int r = 0; r < 4; ++r) {
      float inv = 1.f / l_r[r];
      size_t rowoff = qbase + (size_t)(row0 + r) * 768;
      #pragma unroll
      for (int j = 0; j < 4; ++j)
        ctx[rowoff + j * 16 + fr] = acc_o[j][r] * inv;
    }
  }
}

// ---- combine partials for heavy blocks (nseg=8) ----
__global__ __launch_bounds__(256) void attn_combine_k(
    const float* __restrict__ part, float* __restrict__ ctx)
{
  const int hidx = blockIdx.x;
  const int t = threadIdx.x;
  const int n = (hidx & 1) ? 63 : 0;
  const int bh = hidx >> 1;
  const int h = bh % 12, b = bh / 12;
  const size_t qbase = ((size_t)b * 4096 + (size_t)n * 64) * 768 + h * 64;
  const int r = t >> 2, d0 = (t & 3) * 16;
  const float* pb = part + (size_t)hidx * 8 * 4224;
  float mi[8], li[8], m = -1e30f;
  #pragma unroll
  for (int i = 0; i < 8; ++i) {
    mi[i] = pb[i * 4224 + 4096 + r];
    li[i] = pb[i * 4224 + 4160 + r];
    m = fmaxf(m, mi[i]);
  }
  float w8[8], L = 0.f;
  #pragma unroll
  for (int i = 0; i < 8; ++i) { w8[i] = __expf(mi[i] - m); L += li[i] * w8[i]; }
  float inv = 1.f / L;
  #pragma unroll
  for (int dd = 0; dd < 4; ++dd) {
    int d = d0 + dd * 4;
    float4 o = {0.f, 0.f, 0.f, 0.f};
    #pragma unroll
    for (int i = 0; i < 8; ++i) {
      float4 p = *(const float4*)&pb[i * 4224 + r * 64 + d];
      o.x = fmaf(w8[i], p.x, o.x); o.y = fmaf(w8[i], p.y, o.y);
      o.z = fmaf(w8[i], p.z, o.z); o.w = fmaf(w8[i], p.w, o.w);
    }
    o.x *= inv; o.y *= inv; o.z *= inv; o.w *= inv;
    *(float4*)&ctx[qbase + (size_t)r * 768 + d] = o;
  }
}

// ---------------- LayerNorm(a + res) * g + b ----------------
template <typename TR, typename TO>
__global__ __launch_bounds__(256) void ln_kernel(
    const float* __restrict__ a, const TR* __restrict__ res,
    const float* __restrict__ g, const float* __restrict__ bb,
    TO* __restrict__ out)
{
  const int row = blockIdx.x, t = threadIdx.x;
  __shared__ float buf[768];
  __shared__ float rs[4], rss[4];
  const size_t base = (size_t)row * 768;
  float s = 0.f, ss = 0.f;
  for (int c = t; c < 768; c += 256) {
    float rv;
    if constexpr (sizeof(TR) == 2) rv = bf2f(res[base + c]);
    else                           rv = res[base + c];
    float v = a[base + c] + rv;
    buf[c] = v;
    s += v;
    ss = fmaf(v, v, ss);
  }
  #pragma unroll
  for (int off = 32; off > 0; off >>= 1) {
    s  += __shfl_down(s, off, 64);
    ss += __shfl_down(ss, off, 64);
  }
  if ((t & 63) == 0) { rs[t >> 6] = s; rss[t >> 6] = ss; }
  __syncthreads();
  float S  = rs[0] + rs[1] + rs[2] + rs[3];
  float SS = rss[0] + rss[1] + rss[2] + rss[3];
  float mu  = S * (1.f / 768.f);
  float var = SS * (1.f / 768.f) - mu * mu;
  float inv = rsqrtf(var + 1e-5f);
  for (int c = t; c < 768; c += 256) {
    float v = (buf[c] - mu) * inv * g[c] + bb[c];
    if constexpr (sizeof(TO) == 2) out[base + c] = f2bf(v);
    else                           out[base + c] = v;
  }
}

extern "C" void kernel_launch(void* const* d_in, const int* in_sizes, int n_in,
                              void* d_out, int out_size, void* d_ws, size_t ws_size,
                              hipStream_t stream)
{
  const float* x   = (const float*)d_in[0];
  const int*   rnd = (const int*)d_in[1];
  const float* Wq  = (const float*)d_in[2];
  const float* bq  = (const float*)d_in[3];
  const float* Wk  = (const float*)d_in[4];
  const float* bk  = (const float*)d_in[5];
  const float* Wv  = (const float*)d_in[6];
  const float* bv  = (const float*)d_in[7];
  const float* g1  = (const float*)d_in[8];
  const float* be1 = (const float*)d_in[9];
  const float* W1  = (const float*)d_in[10];
  const float* b1  = (const float*)d_in[11];
  const float* W2  = (const float*)d_in[12];
  const float* b2  = (const float*)d_in[13];
  const float* g2  = (const float*)d_in[14];
  const float* be2 = (const float*)d_in[15];
  float* out = (float*)d_out;

  char* W = (char*)d_ws;
  bf* w1t   = (bf*)(W);                 // [3072][768]
  bf* w2t   = (bf*)(W + 4718592);       // [768][3072]
  bf* Kb    = (bf*)(W + 9437184);       // [8192][768], h1 later
  bf* wqkv  = (bf*)(W + 22020096);      // [2304][768]
  bf* xb    = (bf*)(W + 25559040);      // [8192][768]
  bf* Qb    = (bf*)(W + 38141952);      // [8192][768]
  bf* Vb    = (bf*)(W + 50724864);      // [8192][768]
  float* part = (float*)(W + 63307776); // 48*8*4224 f32
  bf* f1    = (bf*)(W + 22020096);      // [8192][3072], overlays dead buffers
  bf* h1    = Kb;
  float* ctx = out;
  float* f2  = out;

  dim3 blk(256);
  cvt_x_k<<<dim3(3072), blk, 0, stream>>>(x, xb);
  tconv3_k<<<dim3(12, 12, 3), blk, 0, stream>>>(Wq, Wk, Wv, wqkv);
  tconv_k<<<dim3(48, 12), blk, 0, stream>>>(W1, w1t,  768, 3072);
  tconv_k<<<dim3(12, 48), blk, 0, stream>>>(W2, w2t, 3072,  768);
  qkv_gl_k<<<dim3(18, 64), blk, 0, stream>>>(xb, wqkv, bq, bk, bv, Qb, Kb, Vb);
  attn5_kernel<<<dim3(48 * 8 + 2 * 12 * 62), blk, 0, stream>>>(
      Qb, Kb, Vb, rnd, ctx, part, 8);
  attn_combine_k<<<dim3(48), blk, 0, stream>>>(part, ctx);
  ln_kernel<float, bf><<<dim3(8192), blk, 0, stream>>>(ctx, x, g1, be1, h1);
  // W1: 8-phase 256x256 (grid 12 x 32 = 384 WGs)
  gemm8_k<<<dim3(12, 32), dim3(512), 0, stream>>>(
      h1, w1t, b1, f1, 8192, 3072, 768, 768);
  // W2: round-17 proven 2-phase
  gl_gemm_k<128, float><<<dim3(6, 64), blk, 0, stream>>>(
      f1, w2t, b2, f2, 8192, 768, 3072, 3072, 0);
  ln_kernel<bf, float><<<dim3(8192), blk, 0, stream>>>(f2, h1, g2, be2, out);
}

// Round 24
// 280.173 us; speedup vs baseline: 1.0143x; 1.0143x over previous
//
#include <hip/hip_runtime.h>
#include <cmath>

// B=2, S=4096, DM=768, H=12, FF=3072, BLOCK=64, NB=64, R=3, d=64
// Round 24: FINAL — revert to round-22 proven config (280.3 us) after the
// 8-phase W1 experiment (r23: 284.2, W1 85us) confirmed the 2-phase + T2
// structure is optimal for these small-K shapes at 2 blocks/CU.

typedef unsigned short bf;
typedef __attribute__((ext_vector_type(8))) short bf16x8;
typedef __attribute__((ext_vector_type(4))) float f32x4;

__device__ __forceinline__ float bf2f(bf u) { return __uint_as_float(((unsigned)u) << 16); }
__device__ __forceinline__ bf f2bf(float f) {
  unsigned x = __float_as_uint(f);
  x += 0x7FFFu + ((x >> 16) & 1u);   // round-to-nearest-even
  return (bf)(x >> 16);
}

// async global->LDS, 16B per lane; LDS dest = wave-uniform base + lane*16
__device__ __forceinline__ void gload16(const bf* g, char* lds) {
  __builtin_amdgcn_global_load_lds(
      (const __attribute__((address_space(1))) void*)g,
      (__attribute__((address_space(3))) void*)lds, 16, 0, 0);
}

// ---- x f32 -> bf16 (8/thread) ----
__global__ __launch_bounds__(256) void cvt_x_k(const float* __restrict__ X,
                                               bf* __restrict__ xb)
{
  size_t i = ((size_t)blockIdx.x * 256 + threadIdx.x) * 8;
  float4 f0 = *(const float4*)&X[i];
  float4 f1 = *(const float4*)&X[i + 4];
  *(ushort4*)&xb[i]     = make_ushort4(f2bf(f0.x), f2bf(f0.y), f2bf(f0.z), f2bf(f0.w));
  *(ushort4*)&xb[i + 4] = make_ushort4(f2bf(f1.x), f2bf(f1.y), f2bf(f1.z), f2bf(f1.w));
}

// ---- W [K][N] f32 -> Wt [N][K] bf16, 64x64 LDS tile ----
__global__ __launch_bounds__(256) void tconv_k(const float* __restrict__ W,
                                               bf* __restrict__ Wt, int K, int N)
{
  __shared__ float tile[64][65];
  const int t = threadIdx.x;
  const int bn = blockIdx.x * 64, bk = blockIdx.y * 64;
  const int r = t >> 2, c0 = (t & 3) * 16;
  #pragma unroll
  for (int i = 0; i < 4; ++i) {
    float4 f = *(const float4*)&W[(size_t)(bk + r) * N + bn + c0 + i * 4];
    tile[r][c0 + i*4 + 0] = f.x; tile[r][c0 + i*4 + 1] = f.y;
    tile[r][c0 + i*4 + 2] = f.z; tile[r][c0 + i*4 + 3] = f.w;
  }
  __syncthreads();
  #pragma unroll
  for (int i = 0; i < 4; ++i) {
    int c = c0 + i * 4;
    ushort4 u = make_ushort4(f2bf(tile[c + 0][r]), f2bf(tile[c + 1][r]),
                             f2bf(tile[c + 2][r]), f2bf(tile[c + 3][r]));
    *(ushort4*)&Wt[(size_t)(bn + r) * K + bk + c] = u;
  }
}

// ---- 3x [768][768] transpose-convert in one launch (z = which matrix) ----
__global__ __launch_bounds__(256) void tconv3_k(const float* __restrict__ Wq,
                                                const float* __restrict__ Wk,
                                                const float* __restrict__ Wv,
                                                bf* __restrict__ Wt)
{
  __shared__ float tile[64][65];
  const float* W = (blockIdx.z == 0) ? Wq : ((blockIdx.z == 1) ? Wk : Wv);
  bf* dst = Wt + (size_t)blockIdx.z * 589824;
  const int t = threadIdx.x;
  const int bn = blockIdx.x * 64, bk = blockIdx.y * 64;
  const int r = t >> 2, c0 = (t & 3) * 16;
  #pragma unroll
  for (int i = 0; i < 4; ++i) {
    float4 f = *(const float4*)&W[(size_t)(bk + r) * 768 + bn + c0 + i * 4];
    tile[r][c0 + i*4 + 0] = f.x; tile[r][c0 + i*4 + 1] = f.y;
    tile[r][c0 + i*4 + 2] = f.z; tile[r][c0 + i*4 + 3] = f.w;
  }
  __syncthreads();
  #pragma unroll
  for (int i = 0; i < 4; ++i) {
    int c = c0 + i * 4;
    ushort4 u = make_ushort4(f2bf(tile[c + 0][r]), f2bf(tile[c + 1][r]),
                             f2bf(tile[c + 2][r]), f2bf(tile[c + 3][r]));
    *(ushort4*)&dst[(size_t)(bn + r) * 768 + bk + c] = u;
  }
}

// ---- 2-phase pipelined GEMM with T2 swizzle (round-17 proven) ----
template <int BN, typename TC>
__global__ __launch_bounds__(256) void gl_gemm_k(
    const bf* __restrict__ A, const bf* __restrict__ Bt,
    const float* __restrict__ bias, TC* __restrict__ C,
    int M, int N, int K, int ldbt, int ep)
{
  constexpr int NJ = BN / 32;
  constexpr int ASZ = 16384;
  constexpr int BSZ = BN * 128;
  __shared__ char smem[2 * (ASZ + BSZ)];
  const int t = threadIdx.x;
  const int bm = blockIdx.y * 128, bn = blockIdx.x * BN;
  const int lane = t & 63, wid = t >> 6;
  const int wm = wid >> 1, wn = wid & 1;
  const int fr = lane & 15, fq = lane >> 4;
  const int lr = lane >> 3;
  const int lksw = (((lane & 7) ^ lr) << 3);  // pre-swizzled k-element offset

  f32x4 acc[4][NJ];
  #pragma unroll
  for (int i = 0; i < 4; ++i)
    #pragma unroll
    for (int j = 0; j < NJ; ++j) acc[i][j] = (f32x4){0.f, 0.f, 0.f, 0.f};

  auto STAGE = [&](int p, int k0) {
    char* sA = smem + p * (ASZ + BSZ);
    char* sB = sA + ASZ;
    #pragma unroll
    for (int c = 0; c < 4; ++c) {
      int chunk = wid * 4 + c;
      gload16(A + (size_t)(bm + chunk * 8 + lr) * K + k0 + lksw, sA + chunk * 1024);
    }
    #pragma unroll
    for (int c = 0; c < NJ; ++c) {
      int chunk = wid * NJ + c;
      gload16(Bt + (size_t)(bn + chunk * 8 + lr) * ldbt + k0 + lksw, sB + chunk * 1024);
    }
  };

  const int T = K >> 6;
  STAGE(0, 0);
  asm volatile("s_waitcnt vmcnt(0)" ::: "memory");
  __builtin_amdgcn_s_barrier();
  __builtin_amdgcn_sched_barrier(0);
  int cur = 0;
  for (int tt = 0; tt < T; ++tt) {
    if (tt + 1 < T) STAGE(cur ^ 1, (tt + 1) * 64);
    __builtin_amdgcn_sched_barrier(0);
    char* sA = smem + cur * (ASZ + BSZ);
    char* sB = sA + ASZ;
    __builtin_amdgcn_s_setprio(1);
    #pragma unroll
    for (int kk = 0; kk < 2; ++kk) {
      const int kb = kk * 64 + fq * 16;
      bf16x8 a[4], b[NJ];
      #pragma unroll
      for (int i = 0; i < 4; ++i) {
        int row = wm * 64 + i * 16 + fr;
        a[i] = *(const bf16x8*)(sA + row * 128 + (kb ^ ((row & 7) << 4)));
      }
      #pragma unroll
      for (int j = 0; j < NJ; ++j) {
        int col = wn * (BN / 2) + j * 16 + fr;
        b[j] = *(const bf16x8*)(sB + col * 128 + (kb ^ ((col & 7) << 4)));
      }
      #pragma unroll
      for (int i = 0; i < 4; ++i)
        #pragma unroll
        for (int j = 0; j < NJ; ++j)
          acc[i][j] = __builtin_amdgcn_mfma_f32_16x16x32_bf16(a[i], b[j], acc[i][j], 0, 0, 0);
    }
    __builtin_amdgcn_s_setprio(0);
    __builtin_amdgcn_sched_barrier(0);
    asm volatile("s_waitcnt vmcnt(0)" ::: "memory");
    __builtin_amdgcn_s_barrier();
    __builtin_amdgcn_sched_barrier(0);
    cur ^= 1;
  }
  #pragma unroll
  for (int j = 0; j < NJ; ++j) {
    int col = bn + wn * (BN / 2) + j * 16 + fr;
    float bias_v = bias ? bias[col] : 0.f;
    #pragma unroll
    for (int i = 0; i < 4; ++i) {
      int row0 = bm + wm * 64 + i * 16 + fq * 4;
      #pragma unroll
      for (int r = 0; r < 4; ++r) {
        float v = acc[i][j][r] + bias_v;
        if (ep == 1) v = 0.5f * v * (1.0f + erff(v * 0.70710678118654752f));
        if constexpr (sizeof(TC) == 2) C[(size_t)(row0 + r) * N + col] = f2bf(v);
        else                           C[(size_t)(row0 + r) * N + col] = v;
      }
    }
  }
}

// ---- QKV GEMM, same pipeline + swizzle; N=2304 over [Wq|Wk|Wv]^T ----
__global__ __launch_bounds__(256) void qkv_gl_k(
    const bf* __restrict__ A, const bf* __restrict__ Bt,
    const float* __restrict__ bq, const float* __restrict__ bk,
    const float* __restrict__ bv,
    bf* __restrict__ Qo, bf* __restrict__ Ko, bf* __restrict__ Vo)
{
  constexpr int ASZ = 16384, BSZ = 16384;
  __shared__ char smem[2 * (ASZ + BSZ)];
  const int t = threadIdx.x;
  const int bm = blockIdx.y * 128, bn = blockIdx.x * 128;
  const int lane = t & 63, wid = t >> 6;
  const int wm = wid >> 1, wn = wid & 1;
  const int fr = lane & 15, fq = lane >> 4;
  const int lr = lane >> 3;
  const int lksw = (((lane & 7) ^ lr) << 3);
  const int K = 768;

  f32x4 acc[4][4];
  #pragma unroll
  for (int i = 0; i < 4; ++i)
    #pragma unroll
    for (int j = 0; j < 4; ++j) acc[i][j] = (f32x4){0.f, 0.f, 0.f, 0.f};

  auto STAGE = [&](int p, int k0) {
    char* sA = smem + p * (ASZ + BSZ);
    char* sB = sA + ASZ;
    #pragma unroll
    for (int c = 0; c < 4; ++c) {
      int chunk = wid * 4 + c;
      gload16(A + (size_t)(bm + chunk * 8 + lr) * K + k0 + lksw, sA + chunk * 1024);
    }
    #pragma unroll
    for (int c = 0; c < 4; ++c) {
      int chunk = wid * 4 + c;
      gload16(Bt + (size_t)(bn + chunk * 8 + lr) * K + k0 + lksw, sB + chunk * 1024);
    }
  };

  STAGE(0, 0);
  asm volatile("s_waitcnt vmcnt(0)" ::: "memory");
  __builtin_amdgcn_s_barrier();
  __builtin_amdgcn_sched_barrier(0);
  int cur = 0;
  for (int tt = 0; tt < 12; ++tt) {
    if (tt + 1 < 12) STAGE(cur ^ 1, (tt + 1) * 64);
    __builtin_amdgcn_sched_barrier(0);
    char* sA = smem + cur * (ASZ + BSZ);
    char* sB = sA + ASZ;
    __builtin_amdgcn_s_setprio(1);
    #pragma unroll
    for (int kk = 0; kk < 2; ++kk) {
      const int kb = kk * 64 + fq * 16;
      bf16x8 a[4], b[4];
      #pragma unroll
      for (int i = 0; i < 4; ++i) {
        int row = wm * 64 + i * 16 + fr;
        a[i] = *(const bf16x8*)(sA + row * 128 + (kb ^ ((row & 7) << 4)));
      }
      #pragma unroll
      for (int j = 0; j < 4; ++j) {
        int col = wn * 64 + j * 16 + fr;
        b[j] = *(const bf16x8*)(sB + col * 128 + (kb ^ ((col & 7) << 4)));
      }
      #pragma unroll
      for (int i = 0; i < 4; ++i)
        #pragma unroll
        for (int j = 0; j < 4; ++j)
          acc[i][j] = __builtin_amdgcn_mfma_f32_16x16x32_bf16(a[i], b[j], acc[i][j], 0, 0, 0);
    }
    __builtin_amdgcn_s_setprio(0);
    __builtin_amdgcn_sched_barrier(0);
    asm volatile("s_waitcnt vmcnt(0)" ::: "memory");
    __builtin_amdgcn_s_barrier();
    __builtin_amdgcn_sched_barrier(0);
    cur ^= 1;
  }
  const int seg = bn / 768;
  const int cb  = bn - seg * 768;
  bf* dst = (seg == 0) ? Qo : ((seg == 1) ? Ko : Vo);
  const float* bias = (seg == 0) ? bq : ((seg == 1) ? bk : bv);
  #pragma unroll
  for (int j = 0; j < 4; ++j) {
    int col = cb + wn * 64 + j * 16 + fr;
    float bias_v = bias[col];
    #pragma unroll
    for (int i = 0; i < 4; ++i) {
      int row0 = bm + wm * 64 + i * 16 + fq * 4;
      #pragma unroll
      for (int r = 0; r < 4; ++r)
        dst[(size_t)(row0 + r) * 768 + col] = f2bf(acc[i][j][r] + bias_v);
    }
  }
}

// stage one prefetched K/V block into LDS buffers
__device__ __forceinline__ void stage_kv(char* bK, char* bVT,
    int kkey, int kd0, int vkey, int w,
    uint4 k0, uint4 k1, uint4 v0, uint4 v1)
{
  const int sw = (kkey & 7) << 4;
  *(uint4*)(bK + kkey * 128 + ((2 * kd0) ^ sw))      = k0;
  *(uint4*)(bK + kkey * 128 + ((2 * kd0 + 16) ^ sw)) = k1;
  union { uint4 q; unsigned short s[8]; } a, c;
  a.q = v0; c.q = v1;
  #pragma unroll
  for (int i = 0; i < 8; ++i) {
    int d = w * 16 + i;
    *(unsigned short*)(bVT + d * 128 + ((2 * vkey) ^ ((d & 7) << 4))) = a.s[i];
  }
  #pragma unroll
  for (int i = 0; i < 8; ++i) {
    int d = w * 16 + 8 + i;
    *(unsigned short*)(bVT + d * 128 + ((2 * vkey) ^ ((d & 7) << 4))) = c.s[i];
  }
}

// ---------------- BigBird attention v5 (round-15/17 proven) ----------------
__global__ __launch_bounds__(256) void attn5_kernel(
    const bf* __restrict__ Q, const bf* __restrict__ K,
    const bf* __restrict__ V, const int* __restrict__ rnd,
    float* __restrict__ ctx, float* __restrict__ part, int nseg)
{
  __shared__ char sQP[8192];
  __shared__ char sKV[2][16384];
  __shared__ int klist[8];
  const int t = threadIdx.x;
  const int lane = t & 63, w = t >> 6;
  const int fr = lane & 15, fq = lane >> 4;
  const int wg = blockIdx.x;
  const int nheavy = 48 * nseg;
  const bool heavy = wg < nheavy;
  int b, h, n, nkb, seg = 0, hidx = 0, segBase = 0;
  if (heavy) {
    hidx = wg / nseg; seg = wg - hidx * nseg;
    n = (hidx & 1) ? 63 : 0;
    int bh = hidx >> 1; h = bh % 12; b = bh / 12;
    nkb = 64 / nseg; segBase = seg * nkb;
  } else {
    int idx = wg - nheavy;
    n = 1 + (idx % 62);
    int bh = idx / 62; h = bh % 12; b = bh / 12;
    nkb = (n == 1 || n == 62) ? 7 : 8;
    if (t == 0) {
      int cnt = 0;
      if (n == 1)       { klist[0]=0; klist[1]=1;  klist[2]=2;  klist[3]=63; cnt=4; }
      else if (n == 62) { klist[0]=0; klist[1]=61; klist[2]=62; klist[3]=63; cnt=4; }
      else              { klist[0]=0; klist[1]=n-1; klist[2]=n; klist[3]=n+1; cnt=4; }
      for (int j = 0; j < 3; ++j) klist[cnt++] = rnd[(h * 62 + (n - 1)) * 3 + j];
      if (n != 1 && n != 62) klist[cnt++] = 63;
    }
  }
  const size_t qbase = ((size_t)b * 4096 + (size_t)n * 64) * 768 + h * 64;

  {
    int row = t >> 2, d0 = (t & 3) * 16;
    const bf* qp = &Q[qbase + (size_t)row * 768 + d0];
    #pragma unroll
    for (int i = 0; i < 2; ++i) {
      int off = row * 128 + ((2 * (d0 + 8 * i)) ^ ((row & 7) << 4));
      *(uint4*)(sQP + off) = *(const uint4*)(qp + 8 * i);
    }
  }
  __syncthreads();
  bf16x8 qf[2];
  {
    int row = w * 16 + fr;
    qf[0] = *(const bf16x8*)(sQP + row * 128 + ((2 * (fq * 8))      ^ ((row & 7) << 4)));
    qf[1] = *(const bf16x8*)(sQP + row * 128 + ((2 * (32 + fq * 8)) ^ ((row & 7) << 4)));
  }

  const int kkey = t >> 2, kd0 = (t & 3) * 16;
  const int vkey = lane;

  uint4 pk0, pk1, pv0, pv1;
  {
    int kb = heavy ? segBase : klist[0];
    size_t kbase = ((size_t)b * 4096 + (size_t)kb * 64) * 768 + h * 64;
    const bf* kp = &K[kbase + (size_t)kkey * 768 + kd0];
    pk0 = *(const uint4*)kp;  pk1 = *(const uint4*)(kp + 8);
    const bf* vp = &V[kbase + (size_t)vkey * 768 + w * 16];
    pv0 = *(const uint4*)vp;  pv1 = *(const uint4*)(vp + 8);
  }
  stage_kv(sKV[0], sKV[0] + 8192, kkey, kd0, vkey, w, pk0, pk1, pv0, pv1);

  float m_r[4] = {-1e30f, -1e30f, -1e30f, -1e30f};
  float l_r[4] = {0.f, 0.f, 0.f, 0.f};
  f32x4 acc_o[4];
  #pragma unroll
  for (int j = 0; j < 4; ++j) acc_o[j] = (f32x4){0.f, 0.f, 0.f, 0.f};

  for (int ib = 0; ib < nkb; ++ib) {
    char* bK  = sKV[ib & 1];
    char* bVT = bK + 8192;
    const bool pfv = (ib + 1 < nkb);
    if (pfv) {
      int kb = heavy ? (segBase + ib + 1) : klist[ib + 1];
      size_t kbase = ((size_t)b * 4096 + (size_t)kb * 64) * 768 + h * 64;
      const bf* kp = &K[kbase + (size_t)kkey * 768 + kd0];
      pk0 = *(const uint4*)kp;  pk1 = *(const uint4*)(kp + 8);
      const bf* vp = &V[kbase + (size_t)vkey * 768 + w * 16];
      pv0 = *(const uint4*)vp;  pv1 = *(const uint4*)(vp + 8);
    }
    __syncthreads();
    f32x4 s4[4];
    #pragma unroll
    for (int j = 0; j < 4; ++j) s4[j] = (f32x4){0.f, 0.f, 0.f, 0.f};
    __builtin_amdgcn_s_setprio(1);
    #pragma unroll
    for (int kk = 0; kk < 2; ++kk) {
      #pragma unroll
      for (int j = 0; j < 4; ++j) {
        int key = j * 16 + fr;
        bf16x8 kf = *(const bf16x8*)(bK + key * 128 + ((2 * (kk * 32 + fq * 8)) ^ ((key & 7) << 4)));
        s4[j] = __builtin_amdgcn_mfma_f32_16x16x32_bf16(qf[kk], kf, s4[j], 0, 0, 0);
      }
    }
    __builtin_amdgcn_s_setprio(0);
    #pragma unroll
    for (int j = 0; j < 4; ++j) s4[j] *= 0.125f;
    float c_r[4];
    #pragma unroll
    for (int r = 0; r < 4; ++r) {
      float mx = fmaxf(fmaxf(s4[0][r], s4[1][r]), fmaxf(s4[2][r], s4[3][r]));
      #pragma unroll
      for (int m = 1; m < 16; m <<= 1) mx = fmaxf(mx, __shfl_xor(mx, m, 64));
      float mn = fmaxf(mx, m_r[r]);
      float c  = __expf(m_r[r] - mn);
      float p0 = __expf(s4[0][r] - mn), p1 = __expf(s4[1][r] - mn);
      float p2 = __expf(s4[2][r] - mn), p3 = __expf(s4[3][r] - mn);
      s4[0][r] = p0; s4[1][r] = p1; s4[2][r] = p2; s4[3][r] = p3;
      float sum = p0 + p1 + p2 + p3;
      #pragma unroll
      for (int m = 1; m < 16; m <<= 1) sum += __shfl_xor(sum, m, 64);
      l_r[r] = l_r[r] * c + sum;
      m_r[r] = mn;
      c_r[r] = c;
    }
    #pragma unroll
    for (int j = 0; j < 4; ++j)
      #pragma unroll
      for (int r = 0; r < 4; ++r) acc_o[j][r] *= c_r[r];
    #pragma unroll
    for (int r = 0; r < 4; ++r) {
      int prow = w * 16 + fq * 4 + r;
      int rs = prow * 128, sw = (prow & 7) << 4;
      #pragma unroll
      for (int j = 0; j < 4; ++j)
        *(unsigned short*)(sQP + rs + ((2 * (j * 16 + fr)) ^ sw)) = f2bf(s4[j][r]);
    }
    if (pfv)
      stage_kv(sKV[(ib & 1) ^ 1], sKV[(ib & 1) ^ 1] + 8192, kkey, kd0, vkey, w,
               pk0, pk1, pv0, pv1);
    __builtin_amdgcn_s_setprio(1);
    #pragma unroll
    for (int kk = 0; kk < 2; ++kk) {
      int prow = w * 16 + fr;
      bf16x8 pf8 = *(const bf16x8*)(sQP + prow * 128 + ((2 * (kk * 32 + fq * 8)) ^ ((prow & 7) << 4)));
      #pragma unroll
      for (int j = 0; j < 4; ++j) {
        int col = j * 16 + fr;
        bf16x8 vf = *(const bf16x8*)(bVT + col * 128 + ((2 * (kk * 32 + fq * 8)) ^ ((col & 7) << 4)));
        acc_o[j] = __builtin_amdgcn_mfma_f32_16x16x32_bf16(pf8, vf, acc_o[j], 0, 0, 0);
      }
    }
    __builtin_amdgcn_s_setprio(0);
  }
  if (heavy && nseg > 1) {
    float* pb = part + ((size_t)hidx * nseg + seg) * 4224;
    int row0 = w * 16 + fq * 4;
    #pragma unroll
    for (int r = 0; r < 4; ++r) {
      int row = row0 + r;
      if (fr == 0) { pb[4096 + row] = m_r[r]; pb[4160 + row] = l_r[r]; }
      #pragma unroll
      for (int j = 0; j < 4; ++j)
        pb[row * 64 + j * 16 + fr] = acc_o[j][r];
    }
  } else {
    int row0 = w * 16 + fq * 4;
    #pragma unroll
    for (int r = 0; r < 4; ++r) {
      float inv = 1.f / l_r[r];
      size_t rowoff = qbase + (size_t)(row0 + r) * 768;
      #pragma unroll
      for (int j = 0; j < 4; ++j)
        ctx[rowoff + j * 16 + fr] = acc_o[j][r] * inv;
    }
  }
}

// ---- combine partials for heavy blocks (nseg=8) ----
__global__ __launch_bounds__(256) void attn_combine_k(
    const float* __restrict__ part, float* __restrict__ ctx)
{
  const int hidx = blockIdx.x;
  const int t = threadIdx.x;
  const int n = (hidx & 1) ? 63 : 0;
  const int bh = hidx >> 1;
  const int h = bh % 12, b = bh / 12;
  const size_t qbase = ((size_t)b * 4096 + (size_t)n * 64) * 768 + h * 64;
  const int r = t >> 2, d0 = (t & 3) * 16;
  const float* pb = part + (size_t)hidx * 8 * 4224;
  float mi[8], li[8], m = -1e30f;
  #pragma unroll
  for (int i = 0; i < 8; ++i) {
    mi[i] = pb[i * 4224 + 4096 + r];
    li[i] = pb[i * 4224 + 4160 + r];
    m = fmaxf(m, mi[i]);
  }
  float w8[8], L = 0.f;
  #pragma unroll
  for (int i = 0; i < 8; ++i) { w8[i] = __expf(mi[i] - m); L += li[i] * w8[i]; }
  float inv = 1.f / L;
  #pragma unroll
  for (int dd = 0; dd < 4; ++dd) {
    int d = d0 + dd * 4;
    float4 o = {0.f, 0.f, 0.f, 0.f};
    #pragma unroll
    for (int i = 0; i < 8; ++i) {
      float4 p = *(const float4*)&pb[i * 4224 + r * 64 + d];
      o.x = fmaf(w8[i], p.x, o.x); o.y = fmaf(w8[i], p.y, o.y);
      o.z = fmaf(w8[i], p.z, o.z); o.w = fmaf(w8[i], p.w, o.w);
    }
    o.x *= inv; o.y *= inv; o.z *= inv; o.w *= inv;
    *(float4*)&ctx[qbase + (size_t)r * 768 + d] = o;
  }
}

// ---------------- LayerNorm(a + res) * g + b ----------------
template <typename TR, typename TO>
__global__ __launch_bounds__(256) void ln_kernel(
    const float* __restrict__ a, const TR* __restrict__ res,
    const float* __restrict__ g, const float* __restrict__ bb,
    TO* __restrict__ out)
{
  const int row = blockIdx.x, t = threadIdx.x;
  __shared__ float buf[768];
  __shared__ float rs[4], rss[4];
  const size_t base = (size_t)row * 768;
  float s = 0.f, ss = 0.f;
  for (int c = t; c < 768; c += 256) {
    float rv;
    if constexpr (sizeof(TR) == 2) rv = bf2f(res[base + c]);
    else                           rv = res[base + c];
    float v = a[base + c] + rv;
    buf[c] = v;
    s += v;
    ss = fmaf(v, v, ss);
  }
  #pragma unroll
  for (int off = 32; off > 0; off >>= 1) {
    s  += __shfl_down(s, off, 64);
    ss += __shfl_down(ss, off, 64);
  }
  if ((t & 63) == 0) { rs[t >> 6] = s; rss[t >> 6] = ss; }
  __syncthreads();
  float S  = rs[0] + rs[1] + rs[2] + rs[3];
  float SS = rss[0] + rss[1] + rss[2] + rss[3];
  float mu  = S * (1.f / 768.f);
  float var = SS * (1.f / 768.f) - mu * mu;
  float inv = rsqrtf(var + 1e-5f);
  for (int c = t; c < 768; c += 256) {
    float v = (buf[c] - mu) * inv * g[c] + bb[c];
    if constexpr (sizeof(TO) == 2) out[base + c] = f2bf(v);
    else                           out[base + c] = v;
  }
}

extern "C" void kernel_launch(void* const* d_in, const int* in_sizes, int n_in,
                              void* d_out, int out_size, void* d_ws, size_t ws_size,
                              hipStream_t stream)
{
  const float* x   = (const float*)d_in[0];
  const int*   rnd = (const int*)d_in[1];
  const float* Wq  = (const float*)d_in[2];
  const float* bq  = (const float*)d_in[3];
  const float* Wk  = (const float*)d_in[4];
  const float* bk  = (const float*)d_in[5];
  const float* Wv  = (const float*)d_in[6];
  const float* bv  = (const float*)d_in[7];
  const float* g1  = (const float*)d_in[8];
  const float* be1 = (const float*)d_in[9];
  const float* W1  = (const float*)d_in[10];
  const float* b1  = (const float*)d_in[11];
  const float* W2  = (const float*)d_in[12];
  const float* b2  = (const float*)d_in[13];
  const float* g2  = (const float*)d_in[14];
  const float* be2 = (const float*)d_in[15];
  float* out = (float*)d_out;

  char* W = (char*)d_ws;
  bf* w1t   = (bf*)(W);                 // [3072][768]
  bf* w2t   = (bf*)(W + 4718592);       // [768][3072]
  bf* Kb    = (bf*)(W + 9437184);       // [8192][768], h1 later
  bf* wqkv  = (bf*)(W + 22020096);      // [2304][768]
  bf* xb    = (bf*)(W + 25559040);      // [8192][768]
  bf* Qb    = (bf*)(W + 38141952);      // [8192][768]
  bf* Vb    = (bf*)(W + 50724864);      // [8192][768]
  float* part = (float*)(W + 63307776); // 48*8*4224 f32
  bf* f1    = (bf*)(W + 22020096);      // [8192][3072], overlays dead buffers
  bf* h1    = Kb;
  float* ctx = out;
  float* f2  = out;

  dim3 blk(256);
  cvt_x_k<<<dim3(3072), blk, 0, stream>>>(x, xb);
  tconv3_k<<<dim3(12, 12, 3), blk, 0, stream>>>(Wq, Wk, Wv, wqkv);
  tconv_k<<<dim3(48, 12), blk, 0, stream>>>(W1, w1t,  768, 3072);
  tconv_k<<<dim3(12, 48), blk, 0, stream>>>(W2, w2t, 3072,  768);
  qkv_gl_k<<<dim3(18, 64), blk, 0, stream>>>(xb, wqkv, bq, bk, bv, Qb, Kb, Vb);
  attn5_kernel<<<dim3(48 * 8 + 2 * 12 * 62), blk, 0, stream>>>(
      Qb, Kb, Vb, rnd, ctx, part, 8);
  attn_combine_k<<<dim3(48), blk, 0, stream>>>(part, ctx);
  ln_kernel<float, bf><<<dim3(8192), blk, 0, stream>>>(ctx, x, g1, be1, h1);
  gl_gemm_k<128, bf><<<dim3(24, 64), blk, 0, stream>>>(
      h1, w1t, b1, f1, 8192, 3072, 768, 768, 1);
  gl_gemm_k<128, float><<<dim3(6, 64), blk, 0, stream>>>(
      f1, w2t, b2, f2, 8192, 768, 3072, 3072, 0);
  ln_kernel<bf, float><<<dim3(8192), blk, 0, stream>>>(f2, h1, g2, be2, out);
}